// Round 3
// baseline (277.797 us; speedup 1.0000x reference)
//
#include <hip/hip_runtime.h>
#include <hip/hip_fp16.h>
#include <math.h>

#define BN_EPS 1e-5f

typedef _Float16 half8 __attribute__((ext_vector_type(8)));
typedef float floatx4 __attribute__((ext_vector_type(4)));

#define MFMA16H(a, b, c) __builtin_amdgcn_mfma_f32_16x16x32_f16((a), (b), (c), 0, 0, 0)

__device__ __forceinline__ unsigned short f2h(float x) {
    return __half_as_ushort(__float2half(x));
}
__device__ __forceinline__ float h2f(unsigned short b) {
    return __half2float(__ushort_as_half(b));
}

// ---------------------------------------------------------------------------
// prep: blocks [0,64) pack weights; [64,128) zero deg; rest convert x->fp16
// into the SPLIT layout (xhA = features 0..31, xhB = 32..63; 64-B rows).
// ---------------------------------------------------------------------------
__global__ void prep_kernel(const float* __restrict__ W1, const float* __restrict__ b1,
                            const float* __restrict__ g1, const float* __restrict__ bt1,
                            const float* __restrict__ m1, const float* __restrict__ v1,
                            const float* __restrict__ W2, const float* __restrict__ b2,
                            const float* __restrict__ gc, const float* __restrict__ bc,
                            const float* __restrict__ mc, const float* __restrict__ vc,
                            const float* __restrict__ l1W, const float* __restrict__ l1b,
                            const float* __restrict__ gbn, const float* __restrict__ bbn,
                            const float* __restrict__ mbn, const float* __restrict__ vbn,
                            const float* __restrict__ l2W, const float* __restrict__ l2b,
                            unsigned short* __restrict__ w1p, unsigned short* __restrict__ w2p,
                            float* __restrict__ bias1, float* __restrict__ bias2,
                            unsigned short* __restrict__ w1ph, unsigned short* __restrict__ w2ph,
                            float* __restrict__ bias1h, float* __restrict__ bias2h,
                            int* __restrict__ deg,
                            const float* __restrict__ x,
                            unsigned short* __restrict__ xhA, unsigned short* __restrict__ xhB,
                            int N) {
    int b = blockIdx.x, t = threadIdx.x;
    if (b >= 128) {                      // ---- x2h (split layout) ----
        int i = (b - 128) * 256 + t;
        if (i < N * 16) {
            float4 v = ((const float4*)x)[i];
            ushort4 o;
            o.x = f2h(v.x); o.y = f2h(v.y); o.z = f2h(v.z); o.w = f2h(v.w);
            int node = i >> 4;
            int f = (i & 15) * 4;
            unsigned short* dst = (f < 32) ? (xhA + (size_t)node * 32 + f)
                                           : (xhB + (size_t)node * 32 + (f - 32));
            *(ushort4*)dst = o;
        }
        return;
    }
    if (b >= 64) {                       // ---- zero deg ----
        for (int i = (b - 64) * 256 + t; i < N; i += 64 * 256) deg[i] = 0;
        return;
    }
    // ---- pack (BN folded, fp16 hi/lo split, MFMA B-frag order) ----
    int l = b >> 4, chunk = b & 15;
    if (l < 3) {
        const float* W1l = W1 + (size_t)l * 64 * 128;
        const float* W2l = W2 + (size_t)l * 128 * 64;
        if (chunk == 0) {
            if (t < 128) {
                float s = g1[l * 128 + t] * rsqrtf(v1[l * 128 + t] + BN_EPS);
                bias1[l * 128 + t] = (b1[l * 128 + t] - m1[l * 128 + t]) * s + bt1[l * 128 + t];
            }
            if (t < 64) {
                float s = gc[l * 64 + t] * rsqrtf(vc[l * 64 + t] + BN_EPS);
                bias2[l * 64 + t] = (b2[l * 64 + t] - mc[l * 64 + t]) * s + bc[l * 64 + t];
            }
        }
        for (int idx = chunk * 1024 + t; idx < chunk * 1024 + 1024; idx += 256) {
            int j = idx & 7, lane = (idx >> 3) & 63, hl = (idx >> 9) & 1;
            int kk = (idx >> 10) & 1, ct = idx >> 11;
            int k = kk * 32 + (lane >> 4) * 8 + j;
            int nn = ct * 16 + (lane & 15);
            float s = g1[l * 128 + nn] * rsqrtf(v1[l * 128 + nn] + BN_EPS);
            float w = W1l[k * 128 + nn] * s;
            unsigned short hi = f2h(w);
            w1p[(size_t)l * 16384 + idx] = hl ? f2h(w - h2f(hi)) : hi;
        }
        for (int idx = chunk * 1024 + t; idx < chunk * 1024 + 1024; idx += 256) {
            int j = idx & 7, lane = (idx >> 3) & 63, hl = (idx >> 9) & 1;
            int kk = (idx >> 10) & 3, ct = idx >> 12;
            int k = kk * 32 + (lane >> 4) * 8 + j;
            int nn = ct * 16 + (lane & 15);
            float s = gc[l * 64 + nn] * rsqrtf(vc[l * 64 + nn] + BN_EPS);
            float w = W2l[k * 64 + nn] * s;
            unsigned short hi = f2h(w);
            w2p[(size_t)l * 16384 + idx] = hl ? f2h(w - h2f(hi)) : hi;
        }
    } else {
        if (chunk == 0 && t < 64) {
            float s = gbn[t] * rsqrtf(vbn[t] + BN_EPS);
            bias1h[t] = (l1b[t] - mbn[t]) * s + bbn[t];
            bias2h[t] = (t < 40) ? l2b[t] : 0.0f;
        }
        for (int idx = chunk * 512 + t; idx < chunk * 512 + 512; idx += 256) {
            int j = idx & 7, lane = (idx >> 3) & 63, hl = (idx >> 9) & 1;
            int kk = (idx >> 10) & 1, ct = idx >> 11;
            int k = kk * 32 + (lane >> 4) * 8 + j;
            int nn = ct * 16 + (lane & 15);
            float s = gbn[nn] * rsqrtf(vbn[nn] + BN_EPS);
            float w = l1W[k * 64 + nn] * s;
            unsigned short hi = f2h(w);
            w1ph[idx] = hl ? f2h(w - h2f(hi)) : hi;
        }
        for (int idx = chunk * 512 + t; idx < chunk * 512 + 512; idx += 256) {
            int j = idx & 7, lane = (idx >> 3) & 63, hl = (idx >> 9) & 1;
            int kk = (idx >> 10) & 1, ct = idx >> 11;
            int k = kk * 32 + (lane >> 4) * 8 + j;
            int nn = ct * 16 + (lane & 15);
            float w = (nn < 40) ? l2W[k * 40 + nn] : 0.0f;
            unsigned short hi = f2h(w);
            w2ph[idx] = hl ? f2h(w - h2f(hi)) : hi;
        }
    }
}

// ---------------------------------------------------------------------------
// Build: single-pass padded-bucket append. XCD-partitioned by dst range.
// ---------------------------------------------------------------------------
__global__ void build_kernel(const int* __restrict__ ei, int* __restrict__ deg,
                             int* __restrict__ slots, int E, int n) {
    int part = blockIdx.x & 7;
    int lo = (int)((long long)part * n >> 3);
    int hi = (int)((long long)(part + 1) * n >> 3);
    int stride = (gridDim.x >> 3) * 256;
    for (int e = (blockIdx.x >> 3) * 256 + threadIdx.x; e < E; e += stride) {
        int d = ei[E + e];
        if (d >= lo && d < hi) {
            int c = atomicAdd(&deg[d], 1);
            if (c < 64) slots[(size_t)d * 64 + c] = ei[e];
        }
    }
}

// ---------------------------------------------------------------------------
// Gather R10: L2-resident feature-split. Blocks with (blockIdx&7) in 0..3
// gather feature-half A, 4..7 gather half B. Each XCD's read working set is
// one 3.2 MB half-array (< 4 MiB private L2) instead of 6.4 MB (thrash).
// Wave = 8 groups x 8 lanes; group handles one node; lane holds a 4-feature
// slice (8 B). 8 neighbor half-rows in flight per group (64/wave). Slot
// reads nontemporal (single-use stream); hhi/hlo stores nontemporal
// (consumed cross-XCD -> local L2 can't serve them anyway; avoids evicting
// the resident xin half). Invalid tail rows redirect to the node's own
// (hot) row with masked accumulate — loads stay unconditional.
// ---------------------------------------------------------------------------
__device__ __forceinline__ void acc4(float* a, uint2 v) {
    float2 p = __half22float2(*(const __half2*)&v.x);
    float2 q = __half22float2(*(const __half2*)&v.y);
    a[0] += p.x; a[1] += p.y; a[2] += q.x; a[3] += q.y;
}

__global__ __launch_bounds__(256)
void gather_kernel(const unsigned short* __restrict__ xA, const unsigned short* __restrict__ xB,
                   const int* __restrict__ slots, const int* __restrict__ deg,
                   unsigned short* __restrict__ hhi,
                   unsigned short* __restrict__ hlo, int n) {
    int b = blockIdx.x;
    int xcd = b & 7;
    int fh = xcd >> 2;                       // feature half: 0 -> A, 1 -> B
    int whb = (b >> 3) * 4 + (xcd & 3);      // within-half block index
    int wv = threadIdx.x >> 6, lane = threadIdx.x & 63;
    int g = lane >> 3, s8 = lane & 7;
    int node = whb * 32 + wv * 8 + g;
    if (node >= n) return;                   // per-group divergence, no barriers
    const unsigned short* xin = fh ? xB : xA;
    int d = deg[node];
    d = d > 64 ? 64 : d;
    const int* anode = slots + (size_t)node * 64;
    const int gbase = g * 8;

    float a0[4] = {0.f, 0.f, 0.f, 0.f};
    float a1[4] = {0.f, 0.f, 0.f, 0.f};
    float a2[4] = {0.f, 0.f, 0.f, 0.f};
    float a3[4] = {0.f, 0.f, 0.f, 0.f};

    // self (eps=0)
    {
        uint2 v = *(const uint2*)(xin + (size_t)node * 32 + s8 * 4);
        acc4(a0, v);
    }

    for (int base = 0; base < d; base += 8) {
        int m = d - base; if (m > 8) m = 8;
        int myslot = (s8 < m) ? __builtin_nontemporal_load(&anode[base + s8]) : 0;
        int t0 = __shfl(myslot, gbase + 0, 64);
        int t1 = __shfl(myslot, gbase + 1, 64);
        int t2 = __shfl(myslot, gbase + 2, 64);
        int t3 = __shfl(myslot, gbase + 3, 64);
        int t4 = __shfl(myslot, gbase + 4, 64);
        int t5 = __shfl(myslot, gbase + 5, 64);
        int t6 = __shfl(myslot, gbase + 6, 64);
        int t7 = __shfl(myslot, gbase + 7, 64);
        bool k1 = 1 < m, k2 = 2 < m, k3 = 3 < m;
        bool k4 = 4 < m, k5 = 5 < m, k6 = 6 < m, k7 = 7 < m;
        t1 = k1 ? t1 : node; t2 = k2 ? t2 : node; t3 = k3 ? t3 : node;
        t4 = k4 ? t4 : node; t5 = k5 ? t5 : node; t6 = k6 ? t6 : node;
        t7 = k7 ? t7 : node;
        uint2 v0 = *(const uint2*)(xin + (size_t)t0 * 32 + s8 * 4);
        uint2 v1 = *(const uint2*)(xin + (size_t)t1 * 32 + s8 * 4);
        uint2 v2 = *(const uint2*)(xin + (size_t)t2 * 32 + s8 * 4);
        uint2 v3 = *(const uint2*)(xin + (size_t)t3 * 32 + s8 * 4);
        uint2 v4 = *(const uint2*)(xin + (size_t)t4 * 32 + s8 * 4);
        uint2 v5 = *(const uint2*)(xin + (size_t)t5 * 32 + s8 * 4);
        uint2 v6 = *(const uint2*)(xin + (size_t)t6 * 32 + s8 * 4);
        uint2 v7 = *(const uint2*)(xin + (size_t)t7 * 32 + s8 * 4);
        acc4(a0, v0);
        if (k1) acc4(a1, v1);
        if (k2) acc4(a2, v2);
        if (k3) acc4(a3, v3);
        if (k4) acc4(a0, v4);
        if (k5) acc4(a1, v5);
        if (k6) acc4(a2, v6);
        if (k7) acc4(a3, v7);
    }

    float r[4];
#pragma unroll
    for (int q = 0; q < 4; ++q) r[q] = (a0[q] + a1[q]) + (a2[q] + a3[q]);

    unsigned short h0 = f2h(r[0]), h1 = f2h(r[1]), h2 = f2h(r[2]), h3 = f2h(r[3]);
    unsigned long long hw = (unsigned long long)h0 | ((unsigned long long)h1 << 16)
                          | ((unsigned long long)h2 << 32) | ((unsigned long long)h3 << 48);
    unsigned short l0 = f2h(r[0] - h2f(h0)), l1 = f2h(r[1] - h2f(h1));
    unsigned short l2 = f2h(r[2] - h2f(h2)), l3 = f2h(r[3] - h2f(h3));
    unsigned long long lw = (unsigned long long)l0 | ((unsigned long long)l1 << 16)
                          | ((unsigned long long)l2 << 32) | ((unsigned long long)l3 << 48);
    size_t off = (size_t)node * 64 + fh * 32 + s8 * 4;
    __builtin_nontemporal_store(hw, (unsigned long long*)&hhi[off]);
    __builtin_nontemporal_store(lw, (unsigned long long*)&hlo[off]);
}

// ---------------------------------------------------------------------------
// f16-MFMA GIN MLP (layers 0,1), grid-stride tiles, weights in regs once.
// Output written to the SPLIT layout (xoutA/xoutB).
// ---------------------------------------------------------------------------
__global__ __launch_bounds__(256)
void mlp_mfma(const unsigned short* __restrict__ hhi, const unsigned short* __restrict__ hlo,
              const unsigned short* __restrict__ w1p, const unsigned short* __restrict__ w2p,
              const float* __restrict__ bias1, const float* __restrict__ bias2,
              unsigned short* __restrict__ xoutA, unsigned short* __restrict__ xoutB, int n) {
    __shared__ __attribute__((aligned(16))) unsigned short h2hi[16 * 136];
    __shared__ __attribute__((aligned(16))) unsigned short h2lo[16 * 136];

    const int t = threadIdx.x;
    const int wv = t >> 6, lane = t & 63;
    const int quad = lane >> 4, l16 = lane & 15;

    half8 w1f[2][2][2];
#pragma unroll
    for (int c = 0; c < 2; ++c)
#pragma unroll
        for (int kk = 0; kk < 2; ++kk)
#pragma unroll
            for (int hl = 0; hl < 2; ++hl) {
                int ct = wv * 2 + c;
                w1f[c][kk][hl] = *(const half8*)&w1p[(size_t)(((ct * 2 + kk) * 2 + hl) * 64 + lane) * 8];
            }
    half8 w2f[4][2];
#pragma unroll
    for (int kk = 0; kk < 4; ++kk)
#pragma unroll
        for (int hl = 0; hl < 2; ++hl)
            w2f[kk][hl] = *(const half8*)&w2p[(size_t)(((wv * 4 + kk) * 2 + hl) * 64 + lane) * 8];

    float b1v0 = bias1[(wv * 2 + 0) * 16 + l16];
    float b1v1 = bias1[(wv * 2 + 1) * 16 + l16];
    float b2v  = bias2[wv * 16 + l16];

    // output half for this wave: col2 = wv*16+l16 -> wv<2 => cols 0..31 (A)
    unsigned short* xout = (wv < 2) ? xoutA : xoutB;
    const int c32 = (wv & 1) * 16 + l16;

    for (int tile = blockIdx.x * 16; tile < n; tile += gridDim.x * 16) {
        int arow = tile + l16;
        if (arow >= n) arow = n - 1;

        const unsigned short* hr = hhi + (size_t)arow * 64 + quad * 8;
        const unsigned short* lr = hlo + (size_t)arow * 64 + quad * 8;
        half8 ah0 = *(const half8*)hr;
        half8 ah1 = *(const half8*)(hr + 32);
        half8 al0 = *(const half8*)lr;
        half8 al1 = *(const half8*)(lr + 32);

        floatx4 accA0 = {0.f, 0.f, 0.f, 0.f};
        floatx4 accA1 = {0.f, 0.f, 0.f, 0.f};
        accA0 = MFMA16H(ah0, w1f[0][0][0], accA0);
        accA0 = MFMA16H(ah0, w1f[0][0][1], accA0);
        accA0 = MFMA16H(al0, w1f[0][0][0], accA0);
        accA0 = MFMA16H(ah1, w1f[0][1][0], accA0);
        accA0 = MFMA16H(ah1, w1f[0][1][1], accA0);
        accA0 = MFMA16H(al1, w1f[0][1][0], accA0);
        accA1 = MFMA16H(ah0, w1f[1][0][0], accA1);
        accA1 = MFMA16H(ah0, w1f[1][0][1], accA1);
        accA1 = MFMA16H(al0, w1f[1][0][0], accA1);
        accA1 = MFMA16H(ah1, w1f[1][1][0], accA1);
        accA1 = MFMA16H(ah1, w1f[1][1][1], accA1);
        accA1 = MFMA16H(al1, w1f[1][1][0], accA1);

#pragma unroll
        for (int r = 0; r < 4; ++r) {
            int node = quad * 4 + r;
            {
                float v = fmaxf(accA0[r] + b1v0, 0.f);
                unsigned short hi = f2h(v);
                int col = (wv * 2 + 0) * 16 + l16;
                h2hi[node * 136 + col] = hi;
                h2lo[node * 136 + col] = f2h(v - h2f(hi));
            }
            {
                float v = fmaxf(accA1[r] + b1v1, 0.f);
                unsigned short hi = f2h(v);
                int col = (wv * 2 + 1) * 16 + l16;
                h2hi[node * 136 + col] = hi;
                h2lo[node * 136 + col] = f2h(v - h2f(hi));
            }
        }
        __syncthreads();

        floatx4 accB = {0.f, 0.f, 0.f, 0.f};
#pragma unroll
        for (int kk = 0; kk < 4; ++kk) {
            half8 a2h = *(const half8*)&h2hi[l16 * 136 + kk * 32 + quad * 8];
            half8 a2l = *(const half8*)&h2lo[l16 * 136 + kk * 32 + quad * 8];
            accB = MFMA16H(a2h, w2f[kk][0], accB);
            accB = MFMA16H(a2h, w2f[kk][1], accB);
            accB = MFMA16H(a2l, w2f[kk][0], accB);
        }
#pragma unroll
        for (int r = 0; r < 4; ++r) {
            int node = tile + quad * 4 + r;
            if (node < n)
                xout[(size_t)node * 32 + c32] = f2h(fmaxf(accB[r] + b2v, 0.f));
        }
        __syncthreads();
    }
}

// ---------------------------------------------------------------------------
// Layer-3 MLP fused with head: GIN mlp -> lin1+bn+relu -> lin2pad ->
// log_softmax.
// ---------------------------------------------------------------------------
__global__ __launch_bounds__(256)
void mlp_head_mfma(const unsigned short* __restrict__ hhi, const unsigned short* __restrict__ hlo,
                   const unsigned short* __restrict__ w1p, const unsigned short* __restrict__ w2p,
                   const float* __restrict__ bias1, const float* __restrict__ bias2,
                   const unsigned short* __restrict__ w1ph, const unsigned short* __restrict__ w2ph,
                   const float* __restrict__ bias1h, const float* __restrict__ bias2h,
                   float* __restrict__ out, int n) {
    __shared__ __attribute__((aligned(16))) unsigned short h2hi[16 * 136];
    __shared__ __attribute__((aligned(16))) unsigned short h2lo[16 * 136];
    __shared__ __attribute__((aligned(16))) unsigned short xT[16 * 72];
    __shared__ __attribute__((aligned(16))) unsigned short hh2hi[16 * 72];
    __shared__ __attribute__((aligned(16))) unsigned short hh2lo[16 * 72];
    __shared__ float zbuf[16][68];

    const int t = threadIdx.x;
    const int wv = t >> 6, lane = t & 63;
    const int quad = lane >> 4, l16 = lane & 15;

    half8 w1f[2][2][2];
#pragma unroll
    for (int c = 0; c < 2; ++c)
#pragma unroll
        for (int kk = 0; kk < 2; ++kk)
#pragma unroll
            for (int hl = 0; hl < 2; ++hl) {
                int ct = wv * 2 + c;
                w1f[c][kk][hl] = *(const half8*)&w1p[(size_t)(((ct * 2 + kk) * 2 + hl) * 64 + lane) * 8];
            }
    half8 w2f[4][2];
#pragma unroll
    for (int kk = 0; kk < 4; ++kk)
#pragma unroll
        for (int hl = 0; hl < 2; ++hl)
            w2f[kk][hl] = *(const half8*)&w2p[(size_t)(((wv * 4 + kk) * 2 + hl) * 64 + lane) * 8];
    half8 w1fh[2][2], w2fh[2][2];
#pragma unroll
    for (int kk = 0; kk < 2; ++kk)
#pragma unroll
        for (int hl = 0; hl < 2; ++hl) {
            w1fh[kk][hl] = *(const half8*)&w1ph[(size_t)(((wv * 2 + kk) * 2 + hl) * 64 + lane) * 8];
            w2fh[kk][hl] = *(const half8*)&w2ph[(size_t)(((wv * 2 + kk) * 2 + hl) * 64 + lane) * 8];
        }

    float b1v0 = bias1[(wv * 2 + 0) * 16 + l16];
    float b1v1 = bias1[(wv * 2 + 1) * 16 + l16];
    float b2v  = bias2[wv * 16 + l16];
    float b1vh = bias1h[wv * 16 + l16];
    float b2vh = bias2h[wv * 16 + l16];

    for (int tile = blockIdx.x * 16; tile < n; tile += gridDim.x * 16) {
        int arow = tile + l16;
        if (arow >= n) arow = n - 1;

        const unsigned short* hr = hhi + (size_t)arow * 64 + quad * 8;
        const unsigned short* lr = hlo + (size_t)arow * 64 + quad * 8;
        half8 ah0 = *(const half8*)hr;
        half8 ah1 = *(const half8*)(hr + 32);
        half8 al0 = *(const half8*)lr;
        half8 al1 = *(const half8*)(lr + 32);

        floatx4 accA0 = {0.f, 0.f, 0.f, 0.f};
        floatx4 accA1 = {0.f, 0.f, 0.f, 0.f};
        accA0 = MFMA16H(ah0, w1f[0][0][0], accA0);
        accA0 = MFMA16H(ah0, w1f[0][0][1], accA0);
        accA0 = MFMA16H(al0, w1f[0][0][0], accA0);
        accA0 = MFMA16H(ah1, w1f[0][1][0], accA0);
        accA0 = MFMA16H(ah1, w1f[0][1][1], accA0);
        accA0 = MFMA16H(al1, w1f[0][1][0], accA0);
        accA1 = MFMA16H(ah0, w1f[1][0][0], accA1);
        accA1 = MFMA16H(ah0, w1f[1][0][1], accA1);
        accA1 = MFMA16H(al0, w1f[1][0][0], accA1);
        accA1 = MFMA16H(ah1, w1f[1][1][0], accA1);
        accA1 = MFMA16H(ah1, w1f[1][1][1], accA1);
        accA1 = MFMA16H(al1, w1f[1][1][0], accA1);

#pragma unroll
        for (int r = 0; r < 4; ++r) {
            int node = quad * 4 + r;
            {
                float v = fmaxf(accA0[r] + b1v0, 0.f);
                unsigned short hi = f2h(v);
                int col = (wv * 2 + 0) * 16 + l16;
                h2hi[node * 136 + col] = hi;
                h2lo[node * 136 + col] = f2h(v - h2f(hi));
            }
            {
                float v = fmaxf(accA1[r] + b1v1, 0.f);
                unsigned short hi = f2h(v);
                int col = (wv * 2 + 1) * 16 + l16;
                h2hi[node * 136 + col] = hi;
                h2lo[node * 136 + col] = f2h(v - h2f(hi));
            }
        }
        __syncthreads();

        floatx4 accB = {0.f, 0.f, 0.f, 0.f};
#pragma unroll
        for (int kk = 0; kk < 4; ++kk) {
            half8 a2h = *(const half8*)&h2hi[l16 * 136 + kk * 32 + quad * 8];
            half8 a2l = *(const half8*)&h2lo[l16 * 136 + kk * 32 + quad * 8];
            accB = MFMA16H(a2h, w2f[kk][0], accB);
            accB = MFMA16H(a2h, w2f[kk][1], accB);
            accB = MFMA16H(a2l, w2f[kk][0], accB);
        }
        // x (layer-3 output) -> LDS as fp16 (same rounding as global store)
#pragma unroll
        for (int r = 0; r < 4; ++r)
            xT[(quad * 4 + r) * 72 + wv * 16 + l16] = f2h(fmaxf(accB[r] + b2v, 0.f));
        __syncthreads();

        // ---- head stage A: x @ lin1 (A fp16 direct, 2 MFMAs/kk) ----
        half8 ax[2];
#pragma unroll
        for (int kk = 0; kk < 2; ++kk)
            ax[kk] = *(const half8*)&xT[l16 * 72 + kk * 32 + quad * 8];

        floatx4 accH = {0.f, 0.f, 0.f, 0.f};
#pragma unroll
        for (int kk = 0; kk < 2; ++kk) {
            accH = MFMA16H(ax[kk], w1fh[kk][0], accH);
            accH = MFMA16H(ax[kk], w1fh[kk][1], accH);
        }
#pragma unroll
        for (int r = 0; r < 4; ++r) {
            int node = quad * 4 + r;
            float v = fmaxf(accH[r] + b1vh, 0.f);
            unsigned short hi = f2h(v);
            int col = wv * 16 + l16;
            hh2hi[node * 72 + col] = hi;
            hh2lo[node * 72 + col] = f2h(v - h2f(hi));
        }
        __syncthreads();

        // ---- head stage B: @ lin2pad ----
        floatx4 accZ = {0.f, 0.f, 0.f, 0.f};
#pragma unroll
        for (int kk = 0; kk < 2; ++kk) {
            half8 a2h = *(const half8*)&hh2hi[l16 * 72 + kk * 32 + quad * 8];
            half8 a2l = *(const half8*)&hh2lo[l16 * 72 + kk * 32 + quad * 8];
            accZ = MFMA16H(a2h, w2fh[kk][0], accZ);
            accZ = MFMA16H(a2h, w2fh[kk][1], accZ);
            accZ = MFMA16H(a2l, w2fh[kk][0], accZ);
        }
#pragma unroll
        for (int r = 0; r < 4; ++r)
            zbuf[quad * 4 + r][wv * 16 + l16] = accZ[r] + b2vh;
        __syncthreads();

        // ---- log-softmax over 40 classes ----
#pragma unroll
        for (int r = 0; r < 4; ++r) {
            int nl = wv * 4 + r;
            float zi = (lane < 40) ? zbuf[nl][lane] : -INFINITY;
            float mx = zi;
#pragma unroll
            for (int msk = 1; msk < 64; msk <<= 1)
                mx = fmaxf(mx, __shfl_xor(mx, msk, 64));
            float e = (lane < 40) ? __expf(zi - mx) : 0.f;
            float se = e;
#pragma unroll
            for (int msk = 1; msk < 64; msk <<= 1)
                se += __shfl_xor(se, msk, 64);
            float lse = mx + __logf(se);
            int node = tile + nl;
            if (lane < 40 && node < n)
                out[(size_t)node * 40 + lane] = zi - lse;
        }
        __syncthreads();
    }
}

// ---------------------------------------------------------------------------
extern "C" void kernel_launch(void* const* d_in, const int* in_sizes, int n_in,
                              void* d_out, int out_size, void* d_ws, size_t ws_size,
                              hipStream_t stream) {
    const float* x    = (const float*)d_in[0];
    const int*   ei   = (const int*)d_in[1];
    const float* W1   = (const float*)d_in[2];
    const float* b1   = (const float*)d_in[3];
    const float* g1   = (const float*)d_in[4];
    const float* bt1  = (const float*)d_in[5];
    const float* m1   = (const float*)d_in[6];
    const float* v1   = (const float*)d_in[7];
    const float* W2   = (const float*)d_in[8];
    const float* b2   = (const float*)d_in[9];
    const float* gc   = (const float*)d_in[10];
    const float* bc   = (const float*)d_in[11];
    const float* mc   = (const float*)d_in[12];
    const float* vc   = (const float*)d_in[13];
    const float* l1W  = (const float*)d_in[14];
    const float* l1b  = (const float*)d_in[15];
    const float* gbn  = (const float*)d_in[16];
    const float* bbn  = (const float*)d_in[17];
    const float* mbn  = (const float*)d_in[18];
    const float* vbn  = (const float*)d_in[19];
    const float* l2W  = (const float*)d_in[20];
    const float* l2b  = (const float*)d_in[21];
    float* out = (float*)d_out;

    int N = in_sizes[0] / 64;
    int E = in_sizes[1] / 2;

    char* w = (char*)d_ws;
    int* deg = (int*)w;              w += ((size_t)N * 4 + 255) / 256 * 256;
    int* slots = (int*)w;            w += (size_t)N * 64 * 4;
    unsigned short* hhi = (unsigned short*)w;  w += (size_t)N * 64 * 2;
    unsigned short* hlo = (unsigned short*)w;  w += (size_t)N * 64 * 2;
    unsigned short* xh0A = (unsigned short*)w; w += (size_t)N * 32 * 2;
    unsigned short* xh0B = (unsigned short*)w; w += (size_t)N * 32 * 2;
    unsigned short* xh1A = (unsigned short*)w; w += (size_t)N * 32 * 2;
    unsigned short* xh1B = (unsigned short*)w; w += (size_t)N * 32 * 2;
    unsigned short* w1p = (unsigned short*)w;  w += 3 * 16384 * 2;
    unsigned short* w2p = (unsigned short*)w;  w += 3 * 16384 * 2;
    float* bias1 = (float*)w;        w += 3 * 128 * 4;
    float* bias2 = (float*)w;        w += 3 * 64 * 4;
    unsigned short* w1ph = (unsigned short*)w; w += 8192 * 2;
    unsigned short* w2ph = (unsigned short*)w; w += 8192 * 2;
    float* bias1h = (float*)w;       w += 64 * 4;
    float* bias2h = (float*)w;       w += 64 * 4;

    int x2h_blocks = (N * 16 + 255) / 256;
    prep_kernel<<<128 + x2h_blocks, 256, 0, stream>>>(
        W1, b1, g1, bt1, m1, v1, W2, b2, gc, bc, mc, vc,
        l1W, l1b, gbn, bbn, mbn, vbn, l2W, l2b,
        w1p, w2p, bias1, bias2, w1ph, w2ph, bias1h, bias2h,
        deg, x, xh0A, xh0B, N);
    build_kernel<<<2048, 256, 0, stream>>>(ei, deg, slots, E, N);

    // gather grid: 8 XCD residues; residues 0..3 -> half A, 4..7 -> half B.
    int halfBlocks = (N + 31) / 32;          // blocks needed per feature-half
    int Q = (halfBlocks + 3) / 4;            // blocks per XCD residue
    int gather_grid = Q * 8;

    const unsigned short* curA = xh0A;
    const unsigned short* curB = xh0B;
    for (int l = 0; l < 3; ++l) {
        gather_kernel<<<gather_grid, 256, 0, stream>>>(curA, curB, slots, deg,
                                                       hhi, hlo, N);
        if (l < 2) {
            mlp_mfma<<<1024, 256, 0, stream>>>(hhi, hlo,
                                               w1p + (size_t)l * 16384, w2p + (size_t)l * 16384,
                                               bias1 + (size_t)l * 128, bias2 + (size_t)l * 64,
                                               xh1A, xh1B, N);
            curA = xh1A; curB = xh1B;
        } else {
            mlp_head_mfma<<<1024, 256, 0, stream>>>(hhi, hlo,
                                                    w1p + (size_t)2 * 16384, w2p + (size_t)2 * 16384,
                                                    bias1 + (size_t)2 * 128, bias2 + (size_t)2 * 64,
                                                    w1ph, w2ph, bias1h, bias2h, out, N);
        }
    }
}